// Round 10
// baseline (58.269 us; speedup 1.0000x reference)
//
#include <hip/hip_runtime.h>

#define DTF (1.0f/120.0f)

constexpr int Bn = 2048;
constexpr int Tn = 2048;
constexpr int NS = Tn - 1;            // 2047 scan steps
constexpr int ZF = Tn * 3;            // 6144 floats per trajectory
constexpr int NCH = 128;              // time chunks
constexpr int LCH = 16;               // owned steps per chunk (128*16 = 2048 >= 2047)
constexpr int SPAN = 88;              // nominal span; warm-up 72..75 after alignment
constexpr int NSEG = 12;              // 12*8 = 96 >= SPAN + 3 (covers align-down shift)
constexpr int GROWS = NSEG * 8;       // 96 gain rows
constexpr int BT = 64;                // one wave per block
constexpr int GX = Bn / BT;           // 32
constexpr int NBLK = GX * NCH;        // 4096 partials
constexpr int LSTR = 66;              // LDS z slot stride
constexpr int GT_F = GROWS * 8;       // gain-table floats (768)

// ws layout: [0 .. GT_F*4) gain table ; [4096 ..) NBLK doubles (partials)
constexpr int WS_PART = 4096;

// ---- gains: serial 2x2 Riccati from P0, GROWS rows {kx0,kx1,kt0,kt1,isx,ist,det,0} ----
__global__ void gains_kernel(const float* __restrict__ params, float* __restrict__ gt)
{
    if (threadIdx.x != 0) return;
    const float dt = DTF;
    const float damping = params[1];
    const float a = 1.f - dt * damping;
    const float dt2 = dt * dt, a2 = a * a;
    const float qp = 2e-10f, qv = 3e-7f, qth = 1e-2f, qdth = 1e-1f;
    const float Rp = 2.5e-7f, Rt = 9.1e-3f;
    float x00 = 0.01f, x01 = 0.f, x11 = 0.01f;
    float t00 = 0.01f, t01 = 0.f, t11 = 0.01f;
    for (int t = 0; t < GROWS; ++t) {
        float Pp00 = fmaf(dt2, x11, fmaf(2.f * dt, x01, x00)) + qp;
        float Pp01 = a * fmaf(dt, x11, x01);
        float Pp11 = fmaf(a2, x11, qv);
        float Sx = Pp00 + Rp;
        float isx = __builtin_amdgcn_rcpf(Sx);
        float kx0 = Pp00 * isx, kx1 = Pp01 * isx;
        x00 = Pp00 - kx0 * Pp00; x01 = Pp01 - kx0 * Pp01; x11 = Pp11 - kx1 * Pp01;
        float Tp00 = fmaf(dt2, t11, fmaf(2.f * dt, t01, t00)) + qth;
        float Tp01 = fmaf(dt, t11, t01);
        float Tp11 = t11 + qdth;
        float St = Tp00 + Rt;
        float ist = __builtin_amdgcn_rcpf(St);
        float kt0 = Tp00 * ist, kt1 = Tp01 * ist;
        t00 = Tp00 - kt0 * Tp00; t01 = Tp01 - kt0 * Tp01; t11 = Tp11 - kt1 * Tp01;
        float* row = gt + (size_t)t * 8;
        row[0] = kx0; row[1] = kx1; row[2] = kt0; row[3] = kt1;
        row[4] = isx; row[5] = ist; row[6] = Sx * Sx * St; row[7] = 0.f;
    }
}

// ---- main filter: table gains in LDS (broadcast), coalesced transposed z ----
__global__ __launch_bounds__(BT, 4) void ekf_main(const float* __restrict__ params,
                                                  const float* __restrict__ meas,
                                                  const float* __restrict__ gt,
                                                  double* __restrict__ part)
{
    __shared__ float lds[28 * LSTR];         // transposed z window [28 slots][66]
    __shared__ float gtab[GT_F];             // gain rows, chunk-relative

    const int tid = threadIdx.x;
    const int c = blockIdx.y;
    const float dt = DTF;
    const float fric = params[0];
    const float damping = params[1];
    const float a = 1.f - dt * damping;
    const float dfr = dt * fric;
    const float* __restrict__ zt = meas + (size_t)(blockIdx.x * BT) * ZF;

    const int j0   = c * LCH;
    const int jend = min(j0 + LCH, NS);
    int jw = jend - SPAN;
    jw = (jw < 3) ? 0 : (jw - ((jw - 3) & 3));   // jw % 4 == 3, or 0 (exact head)
    const int A0 = (jw * 3 + 3) & ~3;            // aligned base of step windows (d in 0..3)
    const int d  = jw * 3 + 3 - A0;
    const int AI = (jw * 3) & ~3;                // aligned base of init window
    const int di = jw * 3 - AI;

    // gain table -> LDS (coalesced, one pass; same-wave in-order DS => no barrier)
    #pragma unroll
    for (int i = 0; i < GT_F / BT; ++i) gtab[i * BT + tid] = gt[i * BT + tid];

    float4 g[7];
#define LOADF(A) do { \
    _Pragma("unroll") \
    for (int i_ = 0; i_ < 7; ++i_) { \
        int flat_ = i_ * BT + tid; \
        int row_ = flat_ / 7, k_ = flat_ - row_ * 7; \
        int fs_ = min((A) + 4 * k_, ZF - 4); \
        g[i_] = *(const float4*)(zt + (size_t)row_ * ZF + fs_); \
    } \
} while (0)
#define STORELDS() do { \
    _Pragma("unroll") \
    for (int i_ = 0; i_ < 7; ++i_) { \
        int flat_ = i_ * BT + tid; \
        int row_ = flat_ / 7, k_ = flat_ - row_ * 7; \
        int base_ = 4 * k_ * LSTR + row_; \
        lds[base_]            = g[i_].x; \
        lds[base_ + LSTR]     = g[i_].y; \
        lds[base_ + 2*LSTR]   = g[i_].z; \
        lds[base_ + 3*LSTR]   = g[i_].w; \
    } \
} while (0)

    // init window via the coalesced/transpose path
    LOADF(AI);
    STORELDS();
    float i0 = lds[(di+0)*LSTR + tid], i1 = lds[(di+1)*LSTR + tid], i2 = lds[(di+2)*LSTR + tid];
    float i3 = lds[(di+3)*LSTR + tid], i4 = lds[(di+4)*LSTR + tid], i5 = lds[(di+5)*LSTR + tid];
    float s0 = i0, s1 = i1, s4 = i2;
    float s2 = (i3 - i0) / dt, s3 = (i4 - i1) / dt, s5 = (i5 - i2) / dt;

    LOADF(A0);                                   // frame 0 in flight
    float facc = 0.f;

    for (int s = 0; s < NSEG; ++s) {
        const int jb = jw + 8 * s;
        if (jb >= jend) break;                   // head chunks finish early
        STORELDS();
        LOADF(A0 + 24 * (s + 1));                // next frame early (clamped in-bounds)
        __builtin_amdgcn_sched_barrier(0);
        float zv[24];
        #pragma unroll
        for (int k2 = 0; k2 < 24; ++k2) zv[k2] = lds[(d + k2) * LSTR + tid];
        #pragma unroll
        for (int ss = 0; ss < 8; ++ss) {
            const float4 ga = *(const float4*)&gtab[(8 * s + ss) * 8];      // broadcast
            const float4 gb = *(const float4*)&gtab[(8 * s + ss) * 8 + 4];  // broadcast
            float p0 = fmaf(dt, s2, s0), p1 = fmaf(dt, s3, s1), p4 = fmaf(dt, s5, s4);
            float p2 = fmaf(a, s2, -copysignf(dfr, s2));
            float p3 = fmaf(a, s3, -copysignf(dfr, s3));
            float y0 = zv[ss*3+0] - p0, y1 = zv[ss*3+1] - p1, y2 = zv[ss*3+2] - p4;
            s0 = fmaf(ga.x, y0, p0); s1 = fmaf(ga.x, y1, p1);
            s2 = fmaf(ga.y, y0, p2); s3 = fmaf(ga.y, y1, p3);
            s4 = fmaf(ga.z, y2, p4); s5 = fmaf(ga.w, y2, s5);
            int j = jb + ss;
            if (j >= j0 && j < jend)
                facc += gb.z + gb.x * fmaf(y0, y0, y1 * y1) + gb.y * y2 * y2;
        }
    }
#undef STORELDS
#undef LOADF

    // wave reduce -> plain per-block store
    double acc = (double)facc;
    for (int off = 32; off; off >>= 1) acc += __shfl_down(acc, off);
    if (tid == 0) part[blockIdx.y * GX + blockIdx.x] = acc;
}

// ---- finalize: reduce 4096 partials, no atomics ----
__global__ void finalize_kernel(const double* __restrict__ part, float* __restrict__ out)
{
    const int tid = threadIdx.x;               // 1024 threads
    double v = 0.0;
    #pragma unroll
    for (int i = 0; i < NBLK / 1024; ++i) v += part[tid + i * 1024];
    for (int off = 32; off; off >>= 1) v += __shfl_down(v, off);
    __shared__ double wp[16];
    if ((tid & 63) == 0) wp[tid >> 6] = v;
    __syncthreads();
    if (tid == 0) {
        double t = 0.0;
        #pragma unroll
        for (int i = 0; i < 16; ++i) t += wp[i];
        out[0] = (float)(t / ((double)Bn * (double)NS));
    }
}

extern "C" void kernel_launch(void* const* d_in, const int* in_sizes, int n_in,
                              void* d_out, int out_size, void* d_ws, size_t ws_size,
                              hipStream_t stream)
{
    const float* params = (const float*)d_in[0];
    const float* meas = (const float*)d_in[1];
    float* gt = (float*)d_ws;
    double* part = (double*)((char*)d_ws + WS_PART);
    float* out = (float*)d_out;

    hipLaunchKernelGGL(gains_kernel, dim3(1), dim3(64), 0, stream, params, gt);
    hipLaunchKernelGGL(ekf_main, dim3(GX, NCH), dim3(BT), 0, stream, params, meas, gt, part);
    hipLaunchKernelGGL(finalize_kernel, dim3(1), dim3(1024), 0, stream, part, out);
}

// Round 11
// 52.815 us; speedup vs baseline: 1.1033x; 1.1033x over previous
//
#include <hip/hip_runtime.h>

#define DTF (1.0f/120.0f)

constexpr int Bn = 2048;
constexpr int Tn = 2048;
constexpr int NS = Tn - 1;            // 2047 scan steps
constexpr int ZF = Tn * 3;            // 6144 floats per trajectory
constexpr int NCH = 64;               // time chunks
constexpr int LCH = 32;               // owned steps per chunk
constexpr int SPAN = 108;             // warm-up 76..79 after alignment
constexpr int NSEG = 14;              // 14*8 = 112 >= SPAN+3
constexpr int BT = 64;                // one wave per block
constexpr int GX = Bn / BT;           // 32
constexpr int NBLK = GX * NCH;        // 2048 partials
constexpr int RSTR = 30;              // LDS row stride (floats): b64 2-way-free reads

// ---- main filter: row-major LDS (b64 ops), register gains, no gain table ----
__global__ __launch_bounds__(BT, 4) void ekf_main(const float* __restrict__ params,
                                                  const float* __restrict__ meas,
                                                  double* __restrict__ part)
{
    __shared__ float lds[BT * RSTR];          // 7680 B: [row 64][30]

    const int tid = threadIdx.x;
    const int c = blockIdx.y;
    const float dt = DTF;
    const float fric = params[0];
    const float damping = params[1];
    const float a = 1.f - dt * damping;
    const float dfr = dt * fric;
    const float dt2 = dt * dt, a2 = a * a;
    const float qp = 2e-10f, qv = 3e-7f, qth = 1e-2f, qdth = 1e-1f;
    const float Rp = 2.5e-7f, Rt = 9.1e-3f;
    const float* __restrict__ zt = meas + (size_t)(blockIdx.x * BT) * ZF;

    const int j0 = c * LCH;
    const int jend = min(j0 + LCH, NS);
    int jw = jend - SPAN;
    jw = (jw < 3) ? 0 : (jw - ((jw - 3) & 3));   // jw % 4 == 3, or 0 (exact head)
    const int A0 = (jw * 3 + 3) & ~3;            // tail: d==0 (16B-aligned windows)
    const int r0 = j0 - jw, r1 = jend - jw;      // owned window, chunk-relative
    const bool head = (jw == 0);                  // d==3 for head

    // per-lane (row, 4k) staging map: flat = i*64 + tid -> row = flat/7, k = flat%7
    int row_[7], k4_[7];
    #pragma unroll
    for (int i = 0; i < 7; ++i) {
        int flat = i * BT + tid;
        int row = flat / 7;
        row_[i] = row; k4_[i] = 4 * (flat - row * 7);
    }

    float4 g[7];
#define LOADF(A) do { \
    _Pragma("unroll") \
    for (int i_ = 0; i_ < 7; ++i_) { \
        int fs_ = min((A) + k4_[i_], ZF - 4); \
        g[i_] = *(const float4*)(zt + (size_t)row_[i_] * ZF + fs_); \
    } } while (0)
#define STORELDS() do { \
    _Pragma("unroll") \
    for (int i_ = 0; i_ < 7; ++i_) { \
        float* p_ = &lds[row_[i_] * RSTR + k4_[i_]]; \
        *(float2*)p_       = make_float2(g[i_].x, g[i_].y); \
        *(float2*)(p_ + 2) = make_float2(g[i_].z, g[i_].w); \
    } } while (0)

    LOADF(A0);                                   // frame 0 in flight

    // converged gains (tail path): 48-iter 2x2 Riccati, hides frame-0 load latency
    float ckx0, ckx1, ckt0, ckt1, cisx, cist, cdet;
    {
        float x00=0.01f, x01=0.f, x11=0.01f, t00=0.01f, t01=0.f, t11=0.01f;
        for (int t = 0; t < 48; ++t) {
            float Pp00 = fmaf(dt2, x11, fmaf(2.f*dt, x01, x00)) + qp;
            float Pp01 = a * fmaf(dt, x11, x01);
            float Pp11 = fmaf(a2, x11, qv);
            float Sx = Pp00 + Rp, isx = __builtin_amdgcn_rcpf(Sx);
            float kx0 = Pp00*isx, kx1 = Pp01*isx;
            x00 = Pp00-kx0*Pp00; x01 = Pp01-kx0*Pp01; x11 = Pp11-kx1*Pp01;
            float Tp00 = fmaf(dt2, t11, fmaf(2.f*dt, t01, t00)) + qth;
            float Tp01 = fmaf(dt, t11, t01);
            float Tp11 = t11 + qdth;
            float St = Tp00 + Rt, ist = __builtin_amdgcn_rcpf(St);
            float kt0 = Tp00*ist, kt1 = Tp01*ist;
            t00 = Tp00-kt0*Tp00; t01 = Tp01-kt0*Tp01; t11 = Tp11-kt1*Tp01;
            ckx0=kx0; ckx1=kx1; ckt0=kt0; ckt1=kt1; cisx=isx; cist=ist; cdet=Sx*Sx*St;
        }
    }

    STORELDS();                                  // frame 0 -> LDS (in-order DS per wave)
    // init from frame cols 0..5 (head: exactly z[0],z[1]; tail: z[jw+1],z[jw+2] warm-start)
    float b0 = lds[tid*RSTR+0], b1 = lds[tid*RSTR+1], b2 = lds[tid*RSTR+2];
    float b3 = lds[tid*RSTR+3], b4 = lds[tid*RSTR+4], b5 = lds[tid*RSTR+5];
    float s0 = b0, s1 = b1, s4 = b2;
    float s2 = (b3-b0)/dt, s3 = (b4-b1)/dt, s5 = (b5-b2)/dt;

    LOADF(A0 + 24);                              // frame 1 in flight

    float facc = 0.f;                            // head: direct sum
    float accP = 0.f, accT = 0.f, accD = 0.f;    // tail: factored sums
    float hx00=0.01f, hx01=0.f, hx11=0.01f, ht00=0.01f, ht01=0.f, ht11=0.01f;  // head P

#define PREDICT(ZV, SS) \
    float p0 = fmaf(dt, s2, s0), p1 = fmaf(dt, s3, s1), p4 = fmaf(dt, s5, s4); \
    float p2 = fmaf(a, s2, -copysignf(dfr, s2)); \
    float p3 = fmaf(a, s3, -copysignf(dfr, s3)); \
    float y0 = ZV[3*(SS)] - p0, y1 = ZV[3*(SS)+1] - p1, y2 = ZV[3*(SS)+2] - p4;

#define UPDATE(KX0,KX1,KT0,KT1) \
    s0 = fmaf(KX0, y0, p0); s1 = fmaf(KX0, y1, p1); \
    s2 = fmaf(KX1, y0, p2); s3 = fmaf(KX1, y1, p3); \
    s4 = fmaf(KT0, y2, p4); s5 = fmaf(KT1, y2, s5);

    for (int s = 0; ; ++s) {
        __builtin_amdgcn_sched_barrier(0);
        if (!head) {
            float zv[24];
            #pragma unroll
            for (int m = 0; m < 12; ++m) {       // ds_read_b64, 2-way free
                float2 q = *(const float2*)&lds[tid*RSTR + 2*m];
                zv[2*m] = q.x; zv[2*m+1] = q.y;
            }
            #pragma unroll
            for (int ss = 0; ss < 8; ++ss) {
                PREDICT(zv, ss)
                UPDATE(ckx0, ckx1, ckt0, ckt1)
                int r = 8*s + ss;
                if (r >= r0 && r < r1) {
                    accP = fmaf(y0, y0, fmaf(y1, y1, accP));
                    accT = fmaf(y2, y2, accT);
                    accD += cdet;
                }
            }
        } else {
            float zv[24];
            #pragma unroll
            for (int k2 = 0; k2 < 24; ++k2) zv[k2] = lds[tid*RSTR + 3 + k2];
            #pragma unroll
            for (int ss = 0; ss < 8; ++ss) {
                // exact per-step Riccati (head only: <=96 blocks)
                float Pp00 = fmaf(dt2, hx11, fmaf(2.f*dt, hx01, hx00)) + qp;
                float Pp01 = a * fmaf(dt, hx11, hx01);
                float Pp11 = fmaf(a2, hx11, qv);
                float Sx = Pp00 + Rp, isx = __builtin_amdgcn_rcpf(Sx);
                float kx0 = Pp00*isx, kx1 = Pp01*isx;
                hx00 = Pp00-kx0*Pp00; hx01 = Pp01-kx0*Pp01; hx11 = Pp11-kx1*Pp01;
                float Tp00 = fmaf(dt2, ht11, fmaf(2.f*dt, ht01, ht00)) + qth;
                float Tp01 = fmaf(dt, ht11, ht01);
                float Tp11 = ht11 + qdth;
                float St = Tp00 + Rt, ist = __builtin_amdgcn_rcpf(St);
                float kt0 = Tp00*ist, kt1 = Tp01*ist;
                ht00 = Tp00-kt0*Tp00; ht01 = Tp01-kt0*Tp01; ht11 = Tp11-kt1*Tp01;
                PREDICT(zv, ss)
                UPDATE(kx0, kx1, kt0, kt1)
                int r = 8*s + ss;
                if (r >= r0 && r < r1)
                    facc += Sx*Sx*St + isx*fmaf(y0, y0, y1*y1) + ist*y2*y2;
            }
        }
        if (8*(s+1) >= r1 || s+1 >= NSEG) break;
        STORELDS();                              // frame s+1 -> LDS
        LOADF(A0 + 24*(s+2));                    // frame s+2 issue (clamped per-lane)
    }
#undef UPDATE
#undef PREDICT
#undef STORELDS
#undef LOADF

    if (!head) facc = accD + cisx*accP + cist*accT;

    // wave reduce -> plain per-block store (no atomics)
    double acc = (double)facc;
    for (int off = 32; off; off >>= 1) acc += __shfl_down(acc, off);
    if (tid == 0) part[blockIdx.y * GX + blockIdx.x] = acc;
}

// ---- finalize: reduce 2048 partials ----
__global__ void finalize_kernel(const double* __restrict__ part, float* __restrict__ out)
{
    const int tid = threadIdx.x;               // 1024 threads
    double v = part[tid] + part[tid + 1024];
    for (int off = 32; off; off >>= 1) v += __shfl_down(v, off);
    __shared__ double wp[16];
    if ((tid & 63) == 0) wp[tid >> 6] = v;
    __syncthreads();
    if (tid == 0) {
        double t = 0.0;
        #pragma unroll
        for (int i = 0; i < 16; ++i) t += wp[i];
        out[0] = (float)(t / ((double)Bn * (double)NS));
    }
}

extern "C" void kernel_launch(void* const* d_in, const int* in_sizes, int n_in,
                              void* d_out, int out_size, void* d_ws, size_t ws_size,
                              hipStream_t stream)
{
    const float* params = (const float*)d_in[0];
    const float* meas = (const float*)d_in[1];
    double* part = (double*)d_ws;
    float* out = (float*)d_out;

    hipLaunchKernelGGL(ekf_main, dim3(GX, NCH), dim3(BT), 0, stream, params, meas, part);
    hipLaunchKernelGGL(finalize_kernel, dim3(1), dim3(1024), 0, stream, part, out);
}

// Round 12
// 48.338 us; speedup vs baseline: 1.2055x; 1.0926x over previous
//
#include <hip/hip_runtime.h>

#define DTF (1.0f/120.0f)

constexpr int Bn = 2048;
constexpr int Tn = 2048;
constexpr int NS = Tn - 1;            // 2047 scan steps
constexpr int ZF = Tn * 3;            // 6144 floats per trajectory
constexpr int NCH = 64;               // time chunks
constexpr int LCH = 32;               // owned steps per chunk
constexpr int SPAN = 108;             // warm-up 76..79 after alignment
constexpr int NPAIR = 7;              // 7 pairs = 14 segments = 112 steps
constexpr int BT = 64;                // one wave per block
constexpr int GX = Bn / BT;           // 32
constexpr int NBLK = GX * NCH;        // 2048 partials
constexpr int RSTR = 30;              // LDS row stride (floats)

// ---- main filter: 2-deep reg prefetch, XCD-clustered chunks, register gains ----
__global__ __launch_bounds__(BT, 2) void ekf_main(const float* __restrict__ params,
                                                  const float* __restrict__ meas,
                                                  double* __restrict__ part)
{
    __shared__ float lds[BT * RSTR];          // 7680 B: [row 64][30]

    const int tid = threadIdx.x;
    // XCD-clustered decode: xcd = B&7 owns chunk octet c in [xcd*8, xcd*8+8)
    const int B = blockIdx.x;
    const int slot = B >> 3;                  // 0..255
    const int bx = slot >> 3;                 // 0..31 trajectory group
    const int c = (B & 7) * 8 + (slot & 7);   // 0..63 time chunk

    const float dt = DTF;
    const float fric = params[0];
    const float damping = params[1];
    const float a = 1.f - dt * damping;
    const float dfr = dt * fric;
    const float dt2 = dt * dt, a2 = a * a;
    const float qp = 2e-10f, qv = 3e-7f, qth = 1e-2f, qdth = 1e-1f;
    const float Rp = 2.5e-7f, Rt = 9.1e-3f;
    const float* __restrict__ zt = meas + (size_t)(bx * BT) * ZF;

    const int j0 = c * LCH;
    const int jend = min(j0 + LCH, NS);
    int jw = jend - SPAN;
    jw = (jw < 3) ? 0 : (jw - ((jw - 3) & 3));   // jw % 4 == 3, or 0 (exact head)
    const int A0 = (jw * 3 + 3) & ~3;            // tail: 16B-aligned (d==0); head: d==3
    const int r0 = j0 - jw, r1 = jend - jw;
    const bool head = (jw == 0);

    int row_[7], k4_[7];
    #pragma unroll
    for (int i = 0; i < 7; ++i) {
        int flat = i * BT + tid;
        int row = flat / 7;
        row_[i] = row; k4_[i] = 4 * (flat - row * 7);
    }

    float4 g[7], h[7];
#define LOADX(R, A) do { \
    _Pragma("unroll") \
    for (int i_ = 0; i_ < 7; ++i_) { \
        int fs_ = min((A) + k4_[i_], ZF - 4); \
        R[i_] = *(const float4*)(zt + (size_t)row_[i_] * ZF + fs_); \
    } } while (0)
#define STOREX(R) do { \
    _Pragma("unroll") \
    for (int i_ = 0; i_ < 7; ++i_) { \
        float* p_ = &lds[row_[i_] * RSTR + k4_[i_]]; \
        *(float2*)p_       = make_float2(R[i_].x, R[i_].y); \
        *(float2*)(p_ + 2) = make_float2(R[i_].z, R[i_].w); \
    } } while (0)

    LOADX(g, A0);                                // frame 0
    LOADX(h, A0 + 24);                           // frame 1

    // converged gains (tail path): 48-iter 2x2 Riccati hides frame-0 latency
    float ckx0, ckx1, ckt0, ckt1, cisx, cist, cdet;
    {
        float x00=0.01f, x01=0.f, x11=0.01f, t00=0.01f, t01=0.f, t11=0.01f;
        for (int t = 0; t < 48; ++t) {
            float Pp00 = fmaf(dt2, x11, fmaf(2.f*dt, x01, x00)) + qp;
            float Pp01 = a * fmaf(dt, x11, x01);
            float Pp11 = fmaf(a2, x11, qv);
            float Sx = Pp00 + Rp, isx = __builtin_amdgcn_rcpf(Sx);
            float kx0 = Pp00*isx, kx1 = Pp01*isx;
            x00 = Pp00-kx0*Pp00; x01 = Pp01-kx0*Pp01; x11 = Pp11-kx1*Pp01;
            float Tp00 = fmaf(dt2, t11, fmaf(2.f*dt, t01, t00)) + qth;
            float Tp01 = fmaf(dt, t11, t01);
            float Tp11 = t11 + qdth;
            float St = Tp00 + Rt, ist = __builtin_amdgcn_rcpf(St);
            float kt0 = Tp00*ist, kt1 = Tp01*ist;
            t00 = Tp00-kt0*Tp00; t01 = Tp01-kt0*Tp01; t11 = Tp11-kt1*Tp01;
            ckx0=kx0; ckx1=kx1; ckt0=kt0; ckt1=kt1; cisx=isx; cist=ist; cdet=Sx*Sx*St;
        }
    }

    STOREX(g);                                   // frame 0 -> LDS (in-order DS per wave)
    float b0 = lds[tid*RSTR+0], b1 = lds[tid*RSTR+1], b2 = lds[tid*RSTR+2];
    float b3 = lds[tid*RSTR+3], b4 = lds[tid*RSTR+4], b5 = lds[tid*RSTR+5];
    float s0 = b0, s1 = b1, s4 = b2;
    float s2 = (b3-b0)/dt, s3 = (b4-b1)/dt, s5 = (b5-b2)/dt;
    LOADX(g, A0 + 48);                           // frame 2 in flight
    __builtin_amdgcn_sched_barrier(0);

    float facc = 0.f;
    float accP = 0.f, accT = 0.f, accD = 0.f;
    float hx00=0.01f, hx01=0.f, hx11=0.01f, ht00=0.01f, ht01=0.f, ht11=0.01f;

    // consume one 8-step segment s from LDS (uniform s; head path exact Riccati)
    auto consume = [&](int s) {
        if (!head) {
            float zv[24];
            #pragma unroll
            for (int m = 0; m < 12; ++m) {
                float2 q = *(const float2*)&lds[tid*RSTR + 2*m];
                zv[2*m] = q.x; zv[2*m+1] = q.y;
            }
            #pragma unroll
            for (int ss = 0; ss < 8; ++ss) {
                float p0 = fmaf(dt, s2, s0), p1 = fmaf(dt, s3, s1), p4 = fmaf(dt, s5, s4);
                float p2 = fmaf(a, s2, -copysignf(dfr, s2));
                float p3 = fmaf(a, s3, -copysignf(dfr, s3));
                float y0 = zv[3*ss] - p0, y1 = zv[3*ss+1] - p1, y2 = zv[3*ss+2] - p4;
                s0 = fmaf(ckx0, y0, p0); s1 = fmaf(ckx0, y1, p1);
                s2 = fmaf(ckx1, y0, p2); s3 = fmaf(ckx1, y1, p3);
                s4 = fmaf(ckt0, y2, p4); s5 = fmaf(ckt1, y2, s5);
                int r = 8*s + ss;
                if (r >= r0 && r < r1) {
                    accP = fmaf(y0, y0, fmaf(y1, y1, accP));
                    accT = fmaf(y2, y2, accT);
                    accD += cdet;
                }
            }
        } else {
            float zv[24];
            #pragma unroll
            for (int k2 = 0; k2 < 24; ++k2) zv[k2] = lds[tid*RSTR + 3 + k2];
            #pragma unroll
            for (int ss = 0; ss < 8; ++ss) {
                float Pp00 = fmaf(dt2, hx11, fmaf(2.f*dt, hx01, hx00)) + qp;
                float Pp01 = a * fmaf(dt, hx11, hx01);
                float Pp11 = fmaf(a2, hx11, qv);
                float Sx = Pp00 + Rp, isx = __builtin_amdgcn_rcpf(Sx);
                float kx0 = Pp00*isx, kx1 = Pp01*isx;
                hx00 = Pp00-kx0*Pp00; hx01 = Pp01-kx0*Pp01; hx11 = Pp11-kx1*Pp01;
                float Tp00 = fmaf(dt2, ht11, fmaf(2.f*dt, ht01, ht00)) + qth;
                float Tp01 = fmaf(dt, ht11, ht01);
                float Tp11 = ht11 + qdth;
                float St = Tp00 + Rt, ist = __builtin_amdgcn_rcpf(St);
                float kt0 = Tp00*ist, kt1 = Tp01*ist;
                ht00 = Tp00-kt0*Tp00; ht01 = Tp01-kt0*Tp01; ht11 = Tp11-kt1*Tp01;
                float p0 = fmaf(dt, s2, s0), p1 = fmaf(dt, s3, s1), p4 = fmaf(dt, s5, s4);
                float p2 = fmaf(a, s2, -copysignf(dfr, s2));
                float p3 = fmaf(a, s3, -copysignf(dfr, s3));
                float y0 = zv[3*ss] - p0, y1 = zv[3*ss+1] - p1, y2 = zv[3*ss+2] - p4;
                s0 = fmaf(kx0, y0, p0); s1 = fmaf(kx0, y1, p1);
                s2 = fmaf(kx1, y0, p2); s3 = fmaf(kx1, y1, p3);
                s4 = fmaf(kt0, y2, p4); s5 = fmaf(kt1, y2, s5);
                int r = 8*s + ss;
                if (r >= r0 && r < r1)
                    facc += Sx*Sx*St + isx*fmaf(y0, y0, y1*y1) + ist*y2*y2;
            }
        }
    };

    // pair loop: LDS holds frame 2p at loop top; h = frame 2p+1; g-loads = frame 2p+2
    for (int p = 0; ; ++p) {
        consume(2*p);                            // segment 2p from LDS
        if (8*(2*p+1) >= r1) break;
        STOREX(h);                               // frame 2p+1 -> LDS (after reads; waits h)
        LOADX(h, A0 + 24*(2*p+3));               // issue frame 2p+3
        __builtin_amdgcn_sched_barrier(0);
        consume(2*p+1);                          // segment 2p+1
        if (8*(2*p+2) >= r1 || p+1 >= NPAIR) break;
        STOREX(g);                               // frame 2p+2 -> LDS (waits g)
        LOADX(g, A0 + 24*(2*p+4));               // issue frame 2p+4
        __builtin_amdgcn_sched_barrier(0);
    }
#undef STOREX
#undef LOADX

    if (!head) facc = accD + cisx*accP + cist*accT;

    // wave reduce -> plain per-block store (no atomics)
    double acc = (double)facc;
    for (int off = 32; off; off >>= 1) acc += __shfl_down(acc, off);
    if (tid == 0) part[c * GX + bx] = acc;
}

// ---- finalize: reduce 2048 partials ----
__global__ void finalize_kernel(const double* __restrict__ part, float* __restrict__ out)
{
    const int tid = threadIdx.x;               // 1024 threads
    double v = part[tid] + part[tid + 1024];
    for (int off = 32; off; off >>= 1) v += __shfl_down(v, off);
    __shared__ double wp[16];
    if ((tid & 63) == 0) wp[tid >> 6] = v;
    __syncthreads();
    if (tid == 0) {
        double t = 0.0;
        #pragma unroll
        for (int i = 0; i < 16; ++i) t += wp[i];
        out[0] = (float)(t / ((double)Bn * (double)NS));
    }
}

extern "C" void kernel_launch(void* const* d_in, const int* in_sizes, int n_in,
                              void* d_out, int out_size, void* d_ws, size_t ws_size,
                              hipStream_t stream)
{
    const float* params = (const float*)d_in[0];
    const float* meas = (const float*)d_in[1];
    double* part = (double*)d_ws;
    float* out = (float*)d_out;

    hipLaunchKernelGGL(ekf_main, dim3(NBLK), dim3(BT), 0, stream, params, meas, part);
    hipLaunchKernelGGL(finalize_kernel, dim3(1), dim3(1024), 0, stream, part, out);
}

// Round 13
// 37.307 us; speedup vs baseline: 1.5619x; 1.2957x over previous
//
#include <hip/hip_runtime.h>

#define DTF (1.0f/120.0f)

constexpr int Bn = 2048, Tn = 2048, NS = Tn - 1, ZF = Tn * 3;
constexpr int NCH = 16, LCH = 128;    // 16*128 = 2048 >= 2047
constexpr int SPAN = 208;             // warm-up 80..83 after alignment
constexpr int BT = 64;                // one wave per block
constexpr int GX = Bn / BT;           // 32 trajectory groups
constexpr int NBLK = GX * NCH;        // 512
constexpr int RING = 6;               // LDS ring slots
constexpr int FR_F = 24;              // floats per row per frame (8 steps)
constexpr int SLOT_F = BT * FR_F;     // 1536 floats = 6144 B per slot

// ---- main: global_load_lds ring, swizzled rows, LCH=128 low-amplification ----
__global__ __launch_bounds__(BT, 2) void ekf_main(const float* __restrict__ params,
                                                  const float* __restrict__ meas,
                                                  double* __restrict__ part)
{
    __shared__ __align__(16) float lds[RING * SLOT_F];   // 36 KB
    const int tid = threadIdx.x;
    const int B = blockIdx.x;
    const int m = (B & 7) * 64 + (B >> 3);   // XCD-cluster: same group's chunks co-XCD
    const int g = m >> 4, c = m & 15;

    const float dt = DTF;
    const float fric = params[0];
    const float damping = params[1];
    const float a = 1.f - dt * damping;
    const float dfr = dt * fric;
    const float dt2 = dt * dt, a2 = a * a;
    const float qp = 2e-10f, qv = 3e-7f, qth = 1e-2f, qdth = 1e-1f;
    const float Rp = 2.5e-7f, Rt = 9.1e-3f;
    const char* __restrict__ ztb = (const char*)(meas + (size_t)(g * BT) * ZF);

    const int j0 = c * LCH;
    const int jend = min(j0 + LCH, NS);
    int jw = jend - SPAN;
    jw = (jw < 3) ? 0 : (jw - ((jw - 3) & 3));   // jw % 4 == 3, or 0 (exact head)
    const int A0f = (3 * jw) & ~3;               // frame-0 start float (aligned)
    const int d = 3 * jw + 3 - A0f;              // 4 (tail) or 3 (head)
    const int r0 = j0 - jw, r1 = jend - jw;
    const bool head = (jw == 0);

    // per-lane source precompute: instr i writes LDS unit U=i*64+tid (flat);
    // LDS row rowL=U/6 holds GLOBAL row G=(rowL&15)*4+(rowL>>4)  [digit swap]
    int Gbase[6], u16[6];
    #pragma unroll
    for (int i = 0; i < 6; ++i) {
        int U = i * 64 + tid;
        int rowL = U / 6, u = U - rowL * 6;
        int G = (rowL & 15) * 4 + (rowL >> 4);
        Gbase[i] = G * (ZF * 4);
        u16[i] = u * 16;
    }
    // read side: lane t reads LDS row rho(t) -> gets global row t; 4-way banks
    const int rbase = ((tid & 3) * 16 + (tid >> 2)) * FR_F;

#define ISSUE(F) do { \
    int As4_ = (A0f + 24 * (F)) * 4; \
    float* dst_ = &lds[((F) % RING) * SLOT_F]; \
    _Pragma("unroll") \
    for (int i_ = 0; i_ < 6; ++i_) { \
        int inrow_ = min(As4_ + u16[i_], (ZF - 4) * 4); \
        __builtin_amdgcn_global_load_lds((const void*)(ztb + Gbase[i_] + inrow_), \
                                         (void*)(dst_ + i_ * 256), 16, 0, 0); \
    } } while (0)

    ISSUE(0); ISSUE(1); ISSUE(2); ISSUE(3); ISSUE(4);   // 30 loads in flight

    // converged gains (tail): 48-iter 2x2 Riccati under the prologue loads
    float ckx0, ckx1, ckt0, ckt1, cisx, cist, cdet;
    {
        float x00=0.01f, x01=0.f, x11=0.01f, t00=0.01f, t01=0.f, t11=0.01f;
        for (int t = 0; t < 48; ++t) {
            float Pp00 = fmaf(dt2, x11, fmaf(2.f*dt, x01, x00)) + qp;
            float Pp01 = a * fmaf(dt, x11, x01);
            float Pp11 = fmaf(a2, x11, qv);
            float Sx = Pp00 + Rp, isx = __builtin_amdgcn_rcpf(Sx);
            float kx0 = Pp00*isx, kx1 = Pp01*isx;
            x00 = Pp00-kx0*Pp00; x01 = Pp01-kx0*Pp01; x11 = Pp11-kx1*Pp01;
            float Tp00 = fmaf(dt2, t11, fmaf(2.f*dt, t01, t00)) + qth;
            float Tp01 = fmaf(dt, t11, t01);
            float Tp11 = t11 + qdth;
            float St = Tp00 + Rt, ist = __builtin_amdgcn_rcpf(St);
            float kt0 = Tp00*ist, kt1 = Tp01*ist;
            t00 = Tp00-kt0*Tp00; t01 = Tp01-kt0*Tp01; t11 = Tp11-kt1*Tp01;
            ckx0=kx0; ckx1=kx1; ckt0=kt0; ckt1=kt1; cisx=isx; cist=ist; cdet=Sx*Sx*St;
        }
    }

    asm volatile("s_waitcnt vmcnt(24)" ::: "memory");    // frame 0 arrived
    __builtin_amdgcn_sched_barrier(0);

    // init state from frame 0: z[jw] at offset (d-3), z[jw+1] at (d)
    const int ib = d - 3;
    float b0 = lds[rbase+ib], b1 = lds[rbase+ib+1], b2 = lds[rbase+ib+2];
    float b3 = lds[rbase+ib+3], b4 = lds[rbase+ib+4], b5 = lds[rbase+ib+5];
    float s0 = b0, s1 = b1, s4 = b2;
    float s2 = (b3-b0)/dt, s3 = (b4-b1)/dt, s5 = (b5-b2)/dt;

    float facc = 0.f, accP = 0.f, accT = 0.f;
    int nown = 0;
    float hx00=0.01f, hx01=0.f, hx11=0.01f, ht00=0.01f, ht01=0.f, ht11=0.01f;

    for (int s = 0;; ++s) {
        ISSUE(s + 5);                                     // into slot (s-1)%6 (consumed)
        asm volatile("s_waitcnt vmcnt(24)" ::: "memory"); // frames s, s+1 arrived
        __builtin_amdgcn_sched_barrier(0);
        const float* sA = &lds[(s % RING) * SLOT_F + rbase];
        const float* sB = &lds[((s + 1) % RING) * SLOT_F + rbase];
        float zv[24];
        if (!head) {                                      // d == 4: aligned b128 reads
            float4 v0 = *(const float4*)(sA + 4);
            float4 v1 = *(const float4*)(sA + 8);
            float4 v2 = *(const float4*)(sA + 12);
            float4 v3 = *(const float4*)(sA + 16);
            float4 v4 = *(const float4*)(sA + 20);
            float4 v5 = *(const float4*)(sB);
            zv[0]=v0.x; zv[1]=v0.y; zv[2]=v0.z; zv[3]=v0.w;
            zv[4]=v1.x; zv[5]=v1.y; zv[6]=v1.z; zv[7]=v1.w;
            zv[8]=v2.x; zv[9]=v2.y; zv[10]=v2.z; zv[11]=v2.w;
            zv[12]=v3.x; zv[13]=v3.y; zv[14]=v3.z; zv[15]=v3.w;
            zv[16]=v4.x; zv[17]=v4.y; zv[18]=v4.z; zv[19]=v4.w;
            zv[20]=v5.x; zv[21]=v5.y; zv[22]=v5.z; zv[23]=v5.w;
            #pragma unroll
            for (int ss = 0; ss < 8; ++ss) {
                float p0 = fmaf(dt, s2, s0), p1 = fmaf(dt, s3, s1), p4 = fmaf(dt, s5, s4);
                float p2 = fmaf(a, s2, -copysignf(dfr, s2));
                float p3 = fmaf(a, s3, -copysignf(dfr, s3));
                float y0 = zv[3*ss]-p0, y1 = zv[3*ss+1]-p1, y2 = zv[3*ss+2]-p4;
                s0 = fmaf(ckx0, y0, p0); s1 = fmaf(ckx0, y1, p1);
                s2 = fmaf(ckx1, y0, p2); s3 = fmaf(ckx1, y1, p3);
                s4 = fmaf(ckt0, y2, p4); s5 = fmaf(ckt1, y2, s5);
                int r = 8*s + ss;
                if (r >= r0 && r < r1) {
                    accP = fmaf(y0, y0, fmaf(y1, y1, accP));
                    accT = fmaf(y2, y2, accT);
                    ++nown;
                }
            }
        } else {                                          // head: d == 3, exact Riccati
            #pragma unroll
            for (int k = 0; k < 21; ++k) zv[k] = sA[3 + k];
            zv[21] = sB[0]; zv[22] = sB[1]; zv[23] = sB[2];
            #pragma unroll
            for (int ss = 0; ss < 8; ++ss) {
                float Pp00 = fmaf(dt2, hx11, fmaf(2.f*dt, hx01, hx00)) + qp;
                float Pp01 = a * fmaf(dt, hx11, hx01);
                float Pp11 = fmaf(a2, hx11, qv);
                float Sx = Pp00 + Rp, isx = __builtin_amdgcn_rcpf(Sx);
                float kx0 = Pp00*isx, kx1 = Pp01*isx;
                hx00 = Pp00-kx0*Pp00; hx01 = Pp01-kx0*Pp01; hx11 = Pp11-kx1*Pp01;
                float Tp00 = fmaf(dt2, ht11, fmaf(2.f*dt, ht01, ht00)) + qth;
                float Tp01 = fmaf(dt, ht11, ht01);
                float Tp11 = ht11 + qdth;
                float St = Tp00 + Rt, ist = __builtin_amdgcn_rcpf(St);
                float kt0 = Tp00*ist, kt1 = Tp01*ist;
                ht00 = Tp00-kt0*Tp00; ht01 = Tp01-kt0*Tp01; ht11 = Tp11-kt1*Tp01;
                float p0 = fmaf(dt, s2, s0), p1 = fmaf(dt, s3, s1), p4 = fmaf(dt, s5, s4);
                float p2 = fmaf(a, s2, -copysignf(dfr, s2));
                float p3 = fmaf(a, s3, -copysignf(dfr, s3));
                float y0 = zv[3*ss]-p0, y1 = zv[3*ss+1]-p1, y2 = zv[3*ss+2]-p4;
                s0 = fmaf(kx0, y0, p0); s1 = fmaf(kx0, y1, p1);
                s2 = fmaf(kx1, y0, p2); s3 = fmaf(kx1, y1, p3);
                s4 = fmaf(kt0, y2, p4); s5 = fmaf(kt1, y2, s5);
                int r = 8*s + ss;
                if (r >= r0 && r < r1)
                    facc += Sx*Sx*St + isx*fmaf(y0, y0, y1*y1) + ist*y2*y2;
            }
        }
        if (8 * (s + 1) >= r1) break;
    }
    asm volatile("s_waitcnt vmcnt(0)" ::: "memory");      // drain before LDS handoff
#undef ISSUE

    if (!head) facc = (float)nown * cdet + cisx * accP + cist * accT;

    double acc = (double)facc;
    for (int off = 32; off; off >>= 1) acc += __shfl_down(acc, off);
    if (tid == 0) part[m] = acc;
}

// ---- finalize: reduce 512 partials ----
__global__ void finalize_kernel(const double* __restrict__ part, float* __restrict__ out)
{
    const int tid = threadIdx.x;               // 512 threads
    double v = part[tid];
    for (int off = 32; off; off >>= 1) v += __shfl_down(v, off);
    __shared__ double wp[8];
    if ((tid & 63) == 0) wp[tid >> 6] = v;
    __syncthreads();
    if (tid == 0) {
        double t = 0.0;
        #pragma unroll
        for (int i = 0; i < 8; ++i) t += wp[i];
        out[0] = (float)(t / ((double)Bn * (double)NS));
    }
}

extern "C" void kernel_launch(void* const* d_in, const int* in_sizes, int n_in,
                              void* d_out, int out_size, void* d_ws, size_t ws_size,
                              hipStream_t stream)
{
    const float* params = (const float*)d_in[0];
    const float* meas = (const float*)d_in[1];
    double* part = (double*)d_ws;
    float* out = (float*)d_out;

    hipLaunchKernelGGL(ekf_main, dim3(NBLK), dim3(BT), 0, stream, params, meas, part);
    hipLaunchKernelGGL(finalize_kernel, dim3(1), dim3(512), 0, stream, part, out);
}